// Round 1
// baseline (194.222 us; speedup 1.0000x reference)
//
#include <hip/hip_runtime.h>

// out[i] = cos( dot(x[i,:], W) + b ) * cos(phi),  x: [N, 1024] f32
// Pure HBM-bound: 1.074 GB read -> floor ~170 us @ 6.3 TB/s.

constexpr int D            = 1024;
constexpr int F4_PER_ROW   = D / 4;          // 256 float4 per row
constexpr int F4_PER_LANE  = F4_PER_ROW / 64; // 4 float4 per lane

__global__ __launch_bounds__(256) void qhh_kernel(
    const float* __restrict__ x,
    const float* __restrict__ W,
    const float* __restrict__ b,
    const float* __restrict__ phi,
    float* __restrict__ out,
    int nrows)
{
    const int lane        = threadIdx.x & 63;
    const int waves_total = (gridDim.x * blockDim.x) >> 6;
    const int wave0       = (blockIdx.x * blockDim.x + threadIdx.x) >> 6;

    // Hoist W fragment into registers (4 KB total, L2-resident; reused for
    // every row this wave processes).
    const float4* W4 = reinterpret_cast<const float4*>(W);
    float4 wv[F4_PER_LANE];
#pragma unroll
    for (int i = 0; i < F4_PER_LANE; ++i)
        wv[i] = W4[lane + 64 * i];

    const float bias = b[0];
    const float cphi = cosf(phi[0]);

    for (int row = wave0; row < nrows; row += waves_total) {
        const float4* x4 = reinterpret_cast<const float4*>(x + (size_t)row * D);
        float acc = 0.0f;
#pragma unroll
        for (int i = 0; i < F4_PER_LANE; ++i) {
            float4 xv = x4[lane + 64 * i];   // lane-contiguous: 1 KB / wave / instr
            acc = fmaf(xv.x, wv[i].x, acc);
            acc = fmaf(xv.y, wv[i].y, acc);
            acc = fmaf(xv.z, wv[i].z, acc);
            acc = fmaf(xv.w, wv[i].w, acc);
        }
        // 64-lane butterfly reduce
#pragma unroll
        for (int off = 32; off; off >>= 1)
            acc += __shfl_xor(acc, off, 64);

        if (lane == 0)
            out[row] = cosf(acc + bias) * cphi;
    }
}

extern "C" void kernel_launch(void* const* d_in, const int* in_sizes, int n_in,
                              void* d_out, int out_size, void* d_ws, size_t ws_size,
                              hipStream_t stream) {
    const float* x   = (const float*)d_in[0];
    const float* W   = (const float*)d_in[1];
    const float* b   = (const float*)d_in[2];
    const float* phi = (const float*)d_in[3];
    float* out       = (float*)d_out;

    const int nrows = in_sizes[0] / D;   // 262144

    // 2048 blocks x 256 threads = 8192 waves = 32 waves/CU (full occupancy);
    // each wave grid-strides over 32 rows.
    qhh_kernel<<<2048, 256, 0, stream>>>(x, W, b, phi, out, nrows);
}

// Round 3
// 169.376 us; speedup vs baseline: 1.1467x; 1.1467x over previous
//
#include <hip/hip_runtime.h>

// out[i] = cos( dot(x[i,:], W) + b ) * cos(phi),  x: [N, 1024] f32
// HBM-bound: 1.074 GB streamed once -> floor ~170 us @ 6.3 TB/s.
// v2b: 2 contiguous rows per wave-iteration (8 KB contiguous chunk, more MLP)
//      + non-temporal loads on x via clang ext_vector float4 (HIP float4 is a
//        class type the builtin rejects).

constexpr int D           = 1024;
constexpr int F4_PER_LANE = (D / 4) / 64;    // 4 float4 per lane per row

typedef float f32x4 __attribute__((ext_vector_type(4)));

__global__ __launch_bounds__(256) void qhh_kernel(
    const float* __restrict__ x,
    const float* __restrict__ W,
    const float* __restrict__ b,
    const float* __restrict__ phi,
    float* __restrict__ out,
    int nrows)
{
    const int lane        = threadIdx.x & 63;
    const int waves_total = (gridDim.x * blockDim.x) >> 6;
    const int wave0       = (blockIdx.x * blockDim.x + threadIdx.x) >> 6;

    // W (4 KB) hoisted into registers once; L2-resident, reused every row.
    const f32x4* W4 = reinterpret_cast<const f32x4*>(W);
    f32x4 wv[F4_PER_LANE];
#pragma unroll
    for (int i = 0; i < F4_PER_LANE; ++i)
        wv[i] = W4[lane + 64 * i];

    const float bias = b[0];
    const float cphi = cosf(phi[0]);

    const int npairs = nrows >> 1;           // rows processed 2 at a time
    for (int p = wave0; p < npairs; p += waves_total) {
        const int row = 2 * p;
        const f32x4* x0 = reinterpret_cast<const f32x4*>(x + (size_t)row * D);
        const f32x4* x1 = reinterpret_cast<const f32x4*>(x + (size_t)(row + 1) * D);

        // Issue all 8 loads up front (independent, non-temporal: x is
        // streamed exactly once — don't pollute L2/LLC).
        f32x4 a0[F4_PER_LANE], a1[F4_PER_LANE];
#pragma unroll
        for (int i = 0; i < F4_PER_LANE; ++i)
            a0[i] = __builtin_nontemporal_load(&x0[lane + 64 * i]);
#pragma unroll
        for (int i = 0; i < F4_PER_LANE; ++i)
            a1[i] = __builtin_nontemporal_load(&x1[lane + 64 * i]);

        float acc0 = 0.0f, acc1 = 0.0f;
#pragma unroll
        for (int i = 0; i < F4_PER_LANE; ++i) {
            acc0 = fmaf(a0[i].x, wv[i].x, acc0);
            acc0 = fmaf(a0[i].y, wv[i].y, acc0);
            acc0 = fmaf(a0[i].z, wv[i].z, acc0);
            acc0 = fmaf(a0[i].w, wv[i].w, acc0);
            acc1 = fmaf(a1[i].x, wv[i].x, acc1);
            acc1 = fmaf(a1[i].y, wv[i].y, acc1);
            acc1 = fmaf(a1[i].z, wv[i].z, acc1);
            acc1 = fmaf(a1[i].w, wv[i].w, acc1);
        }

        // Two interleaved 64-lane butterfly reductions (independent chains).
#pragma unroll
        for (int off = 32; off; off >>= 1) {
            acc0 += __shfl_xor(acc0, off, 64);
            acc1 += __shfl_xor(acc1, off, 64);
        }

        if (lane == 0) {
            out[row]     = cosf(acc0 + bias) * cphi;
            out[row + 1] = cosf(acc1 + bias) * cphi;
        }
    }
}

extern "C" void kernel_launch(void* const* d_in, const int* in_sizes, int n_in,
                              void* d_out, int out_size, void* d_ws, size_t ws_size,
                              hipStream_t stream) {
    const float* x   = (const float*)d_in[0];
    const float* W   = (const float*)d_in[1];
    const float* b   = (const float*)d_in[2];
    const float* phi = (const float*)d_in[3];
    float* out       = (float*)d_out;

    const int nrows = in_sizes[0] / D;   // 262144

    // 2048 blocks x 256 threads = 8192 waves = 32 waves/CU (full occupancy);
    // each wave handles 16 contiguous-pair chunks (32 rows).
    qhh_kernel<<<2048, 256, 0, stream>>>(x, W, b, phi, out, nrows);
}